// Round 13
// baseline (188.510 us; speedup 1.0000x reference)
//
#include <hip/hip_runtime.h>

#define N_NODES 50000
#define N_EDGES 800000
// dims: in=128, hid=256, out=128

typedef float f32x4 __attribute__((ext_vector_type(4)));
typedef _Float16 half4 __attribute__((ext_vector_type(4)));
typedef _Float16 half8 __attribute__((ext_vector_type(8)));
typedef int iv4 __attribute__((ext_vector_type(4)));

#define NPR 6250          // nodes per XCD range (50000/8)
#define CB 192            // chunk-blocks per XCD for partitioned fill
#define CAP 48            // neighbor-bucket capacity (Poisson(16): P(deg>48)*N ~ 2e-5)

#define ZERO_BLOCKS ((N_NODES + 255) / 256)            // 196
#define CVT_BLOCKS ((N_NODES * 32 + 255) / 256)        // 6250

// ---------------- fused setup: zero counts | prep weights | cvt x->fp16 ----------------
// Logical B1[k][n] = k<128 ? Wl1[n][k] : Wr1[n][k-128]   (layer-1, K-concat)
// Logical B2[k][n] = n<128 ? Wl2[n][k] : Wr2[n-128][k]   (layer-2, N-concat)
// Fragment: fi = ((k>>5)*16 + (n>>4))*64 + (n&15) + 16*((k&31)>>3), elem = k&7

__global__ __launch_bounds__(256) void setup_kernel(
    const float* __restrict__ x, _Float16* __restrict__ x16,
    const float* __restrict__ Wl1, const float* __restrict__ Wr1,
    const float* __restrict__ Wl2, const float* __restrict__ Wr2,
    _Float16* __restrict__ B1h, _Float16* __restrict__ B1l,
    _Float16* __restrict__ B2h, _Float16* __restrict__ B2l,
    int* __restrict__ counts) {
    int bid = blockIdx.x;
    int t = threadIdx.x;
    if (bid < ZERO_BLOCKS) {
        int i = bid * 256 + t;
        if (i < N_NODES) counts[i] = 0;
        return;
    }
    bid -= ZERO_BLOCKS;
    if (bid < 256) {
        int k = bid;   // 0..255
        int n = t;     // 0..255
        float v1 = (k < 128) ? Wl1[n * 128 + k] : Wr1[n * 128 + (k - 128)];
        float v2 = (n < 128) ? Wl2[n * 256 + k] : Wr2[(n - 128) * 256 + k];
        size_t fi = ((size_t)((k >> 5) * 16 + (n >> 4)) * 64 +
                     ((n & 15) + 16 * ((k & 31) >> 3))) * 8 + (k & 7);
        _Float16 h1 = (_Float16)v1;
        _Float16 h2 = (_Float16)v2;
        B1h[fi] = h1; B1l[fi] = (_Float16)(v1 - (float)h1);
        B2h[fi] = h2; B2l[fi] = (_Float16)(v2 - (float)h2);
        return;
    }
    bid -= 256;
    int i = bid * 256 + t;
    if (i < N_NODES * 32) {
        float4 v = reinterpret_cast<const float4*>(x)[i];
        half4 o = {(_Float16)v.x, (_Float16)v.y, (_Float16)v.z, (_Float16)v.w};
        reinterpret_cast<half4*>(x16)[i] = o;
    }
}

// ---------------- bucket-CSR build: one pass, no histogram/scan ----------------
// XCD-partitioned (block i handles dst range (i&7)): counts/eidx lines are
// XCD-exclusive. NT loads on the src/dst STREAMS (zero per-XCD reuse) keep L2
// free for the 1.2 MB/XCD eidx bucket slice, so dirty bucket lines coalesce
// ~16 slot-writes per eviction instead of being evicted partially-dirty.

__global__ __launch_bounds__(256) void fill_kernel(const int* __restrict__ src,
                                                   const int* __restrict__ dst,
                                                   int* __restrict__ counts,
                                                   int* __restrict__ eidx, int E4) {
    int xcd = blockIdx.x & 7;
    int cb = blockIdx.x >> 3;
    int lo = xcd * NPR, hi = lo + NPR;
    int stride = (gridDim.x >> 3) * blockDim.x;  // in int4 units
    const iv4* src4 = reinterpret_cast<const iv4*>(src);
    const iv4* dst4 = reinterpret_cast<const iv4*>(dst);
    for (int q = cb * blockDim.x + threadIdx.x; q < E4; q += stride) {
        iv4 d4 = __builtin_nontemporal_load(&dst4[q]);
        iv4 s4 = __builtin_nontemporal_load(&src4[q]);
#pragma unroll
        for (int u = 0; u < 4; u++) {
            int d = d4[u];
            if (d >= lo && d < hi) {
                int pos = atomicAdd(&counts[d], 1);
                if (pos < CAP) eidx[d * CAP + pos] = s4[u];
            }
        }
    }
}

// ---------------- mean-aggregation gather (one wave per dst node, fp16 rows) ----------------
// OMODE 0: write mean as fp16.  OMODE 1: add mean into fp32 out.

template <int OMODE>
__global__ __launch_bounds__(256) void gather_kernel(
    const int* __restrict__ eidx, const int* __restrict__ counts,
    const _Float16* __restrict__ xin, void* __restrict__ outp) {
    int wid = (blockIdx.x * 256 + threadIdx.x) >> 6;
    int lane = threadIdx.x & 63;
    if (wid >= N_NODES) return;
    int c = counts[wid];
    int end = c < CAP ? c : CAP;
    int base = wid * CAP;
    int half = lane >> 5;
    int c4 = lane & 31;
    float4 acc = {0, 0, 0, 0};
    int j = half;
    for (; j + 6 < end; j += 8) {
        int s0 = eidx[base + j],     s1 = eidx[base + j + 2];
        int s2 = eidx[base + j + 4], s3 = eidx[base + j + 6];
        half4 v0 = *reinterpret_cast<const half4*>(&xin[(size_t)s0 * 128 + c4 * 4]);
        half4 v1 = *reinterpret_cast<const half4*>(&xin[(size_t)s1 * 128 + c4 * 4]);
        half4 v2 = *reinterpret_cast<const half4*>(&xin[(size_t)s2 * 128 + c4 * 4]);
        half4 v3 = *reinterpret_cast<const half4*>(&xin[(size_t)s3 * 128 + c4 * 4]);
        acc.x += (float)v0.x + (float)v1.x + (float)v2.x + (float)v3.x;
        acc.y += (float)v0.y + (float)v1.y + (float)v2.y + (float)v3.y;
        acc.z += (float)v0.z + (float)v1.z + (float)v2.z + (float)v3.z;
        acc.w += (float)v0.w + (float)v1.w + (float)v2.w + (float)v3.w;
    }
    for (; j < end; j += 2) {
        int s0 = eidx[base + j];
        half4 v0 = *reinterpret_cast<const half4*>(&xin[(size_t)s0 * 128 + c4 * 4]);
        acc.x += (float)v0.x; acc.y += (float)v0.y; acc.z += (float)v0.z; acc.w += (float)v0.w;
    }
    acc.x += __shfl_xor(acc.x, 32);
    acc.y += __shfl_xor(acc.y, 32);
    acc.z += __shfl_xor(acc.z, 32);
    acc.w += __shfl_xor(acc.w, 32);
    if (half == 0) {
        float w = 1.0f / fmaxf((float)c, 1.0f);
        if (OMODE == 0) {
            half4 r = {(_Float16)(acc.x * w), (_Float16)(acc.y * w),
                       (_Float16)(acc.z * w), (_Float16)(acc.w * w)};
            *reinterpret_cast<half4*>(&((_Float16*)outp)[(size_t)wid * 128 + c4 * 4]) = r;
        } else {
            float* p = &((float*)outp)[(size_t)wid * 128 + c4 * 4];
            float4 old = *reinterpret_cast<float4*>(p);
            float4 r = {old.x + acc.x * w, old.y + acc.y * w,
                        old.z + acc.z * w, old.w + acc.w * w};
            *reinterpret_cast<float4*>(p) = r;
        }
    }
}

// ---------------- fp16 MFMA GEMM: full-K LDS panel, one barrier, merged N ----------------
// C[M, 256] = A[M, 256] @ B[256, 256] via A*Bh + A*Bl (A exact fp16, fp32 accum).
// MODE 0: A = [A0=agg16 | A1=x16] (K-concat); relu(C + b1) -> O0 = h16 (fp16 [M,256])
// MODE 1: A = A0 = h16; C[:,0:128] -> O0 = z16 (fp16); C[:,128:256]+b2 -> O1 = out (fp32)
// Block: 128 rows x all 256 cols, 512 threads = 8 waves (2 wm x 4 wn);
// per-wave 64x64 out = 4x4 frags of 16x16x32. A panel (128x256 fp16 = 64 KB) staged once.
template <int MODE>
__global__ __launch_bounds__(512, 4) void mfma_gemm_kernel(
    const _Float16* __restrict__ A0, const _Float16* __restrict__ A1,
    const _Float16* __restrict__ Bh, const _Float16* __restrict__ Bl,
    const float* __restrict__ bias, void* __restrict__ O0v, float* __restrict__ O1) {
    __shared__ _Float16 lA[8][8][64][8];  // [kt][m_blk][lane][elem] = 64 KB
    const int tid = threadIdx.x;
    const int lane = tid & 63;
    const int w = tid >> 6;
    const int wm = w >> 2, wn = w & 3;
    const int m0 = blockIdx.x * 128;
    const int nb0 = wn * 4;

    f32x4 acc[4][4];
#pragma unroll
    for (int i = 0; i < 4; i++)
#pragma unroll
        for (int j = 0; j < 4; j++) acc[i][j] = f32x4{0.f, 0.f, 0.f, 0.f};

    // Stage the full 128x256 A panel in fragment order. Thread -> row ms, chunks c0+4i.
    const int ms = tid >> 2;   // 0..127
    const int c0 = tid & 3;    // 16B chunk phase
    {
        int node = m0 + ms;
#pragma unroll
        for (int i = 0; i < 8; i++) {
            int c = c0 + 4 * i;  // 0..31: 16B chunk along K
            const _Float16* Asrc;
            int koff;
            if (MODE == 0) {
                Asrc = (c < 16) ? A0 : A1;
                koff = (c & 15) * 8;
            } else {
                Asrc = A0;
                koff = c * 8;
            }
            half8 v = {0, 0, 0, 0, 0, 0, 0, 0};
            if (node < N_NODES)
                v = *reinterpret_cast<const half8*>(
                    &Asrc[(size_t)node * (MODE == 0 ? 128 : 256) + koff]);
            *reinterpret_cast<half8*>(&lA[c >> 2][ms >> 4][(ms & 15) + 16 * (c & 3)][0]) = v;
        }
    }
    __syncthreads();  // the only barrier

    for (int kt = 0; kt < 8; kt++) {
        half8 ah[4];
#pragma unroll
        for (int mb = 0; mb < 4; mb++)
            ah[mb] = *reinterpret_cast<const half8*>(&lA[kt][wm * 4 + mb][lane][0]);
#pragma unroll
        for (int nb = 0; nb < 4; nb++) {
            size_t fi = ((size_t)(kt * 16 + nb0 + nb) * 64 + lane) * 8;
            half8 vh = *reinterpret_cast<const half8*>(&Bh[fi]);
            half8 vl = *reinterpret_cast<const half8*>(&Bl[fi]);
            __builtin_amdgcn_s_setprio(1);
#pragma unroll
            for (int mb = 0; mb < 4; mb++) {
                acc[mb][nb] = __builtin_amdgcn_mfma_f32_16x16x32_f16(ah[mb], vh, acc[mb][nb], 0, 0, 0);
                acc[mb][nb] = __builtin_amdgcn_mfma_f32_16x16x32_f16(ah[mb], vl, acc[mb][nb], 0, 0, 0);
            }
            __builtin_amdgcn_s_setprio(0);
        }
    }

    // epilogue: C/D layout col = lane&15, row = (lane>>4)*4 + reg
#pragma unroll
    for (int mb = 0; mb < 4; mb++) {
        int rbase = m0 + wm * 64 + mb * 16 + ((lane >> 4) << 2);
#pragma unroll
        for (int nb = 0; nb < 4; nb++) {
            int col = wn * 64 + nb * 16 + (lane & 15);   // 0..255
#pragma unroll
            for (int r = 0; r < 4; r++) {
                int row = rbase + r;
                if (row >= N_NODES) continue;
                float vv = acc[mb][nb][r];
                if (MODE == 0) {
                    ((_Float16*)O0v)[(size_t)row * 256 + col] =
                        (_Float16)fmaxf(vv + bias[col], 0.0f);
                } else {
                    if (col < 128)
                        ((_Float16*)O0v)[(size_t)row * 128 + col] = (_Float16)vv;
                    else
                        O1[(size_t)row * 128 + (col - 128)] = vv + bias[col - 128];
                }
            }
        }
    }
}

extern "C" void kernel_launch(void* const* d_in, const int* in_sizes, int n_in,
                              void* d_out, int out_size, void* d_ws, size_t ws_size,
                              hipStream_t stream) {
    const float* x   = (const float*)d_in[0];
    const int*   ei  = (const int*)d_in[1];
    const float* Wl1 = (const float*)d_in[2];
    const float* Wr1 = (const float*)d_in[3];
    const float* b1  = (const float*)d_in[4];
    const float* Wl2 = (const float*)d_in[5];
    const float* Wr2 = (const float*)d_in[6];
    const float* b2  = (const float*)d_in[7];
    float* out = (float*)d_out;

    const int* srcp = ei;            // edge_index[0]
    const int* dstp = ei + N_EDGES;  // edge_index[1]

    // Workspace layout
    int*      counts = (int*)d_ws;                      // N
    int*      eidx   = counts + N_NODES;                // N*CAP (bucketed CSR)
    _Float16* B1h    = (_Float16*)(eidx + N_NODES * CAP);
    _Float16* B1l    = B1h + 65536;
    _Float16* B2h    = B1l + 65536;
    _Float16* B2l    = B2h + 65536;
    _Float16* agg16  = B2l + 65536;                     // N*128 (reused as z16)
    _Float16* x16    = agg16 + (size_t)N_NODES * 128;   // N*128
    _Float16* h16    = x16 + (size_t)N_NODES * 128;     // N*256
    _Float16* z16    = agg16;                           // alias: agg dead after gemm1

    setup_kernel<<<ZERO_BLOCKS + 256 + CVT_BLOCKS, 256, 0, stream>>>(
        x, x16, Wl1, Wr1, Wl2, Wr2, B1h, B1l, B2h, B2l, counts);
    fill_kernel<<<8 * CB, 256, 0, stream>>>(srcp, dstp, counts, eidx, N_EDGES / 4);

    int ggrid = (N_NODES + 127) / 128;  // 391

    // Layer 1: agg16 = mean-aggr(x16); h16 = relu([agg16|x16]@B1 + b1)
    gather_kernel<0><<<(N_NODES * 64 + 255) / 256, 256, 0, stream>>>(
        eidx, counts, x16, (void*)agg16);
    mfma_gemm_kernel<0><<<ggrid, 512, 0, stream>>>(agg16, x16, B1h, B1l, b1, (void*)h16, nullptr);

    // Layer 2: [z16|pre_out] = h16@B2 (+b2 on out half); out += mean-aggr(z16)
    mfma_gemm_kernel<1><<<ggrid, 512, 0, stream>>>(h16, nullptr, B2h, B2l, b2, (void*)z16, out);
    gather_kernel<1><<<(N_NODES * 64 + 255) / 256, 256, 0, stream>>>(
        eidx, counts, z16, (void*)out);
}

// Round 14
// 187.196 us; speedup vs baseline: 1.0070x; 1.0070x over previous
//
#include <hip/hip_runtime.h>

#define N_NODES 50000
#define N_EDGES 800000
// dims: in=128, hid=256, out=128

typedef float f32x4 __attribute__((ext_vector_type(4)));
typedef _Float16 half4 __attribute__((ext_vector_type(4)));
typedef _Float16 half8 __attribute__((ext_vector_type(8)));
typedef int iv4 __attribute__((ext_vector_type(4)));

#define NPR 6250          // nodes per XCD range (50000/8)
#define CB 256            // chunk-blocks per XCD for partitioned fill
#define CAP 48            // neighbor-bucket capacity (Poisson(16): P(deg>48)*N ~ 5e-8)

#define ZERO_BLOCKS ((N_NODES + 255) / 256)            // 196
#define CVT_BLOCKS ((N_NODES * 32 + 255) / 256)        // 6250

// ---------------- fused setup: zero counts | prep weights | cvt x->fp16 ----------------
// Logical B1[k][n] = k<128 ? Wl1[n][k] : Wr1[n][k-128]   (layer-1, K-concat)
// Logical B2[k][n] = n<128 ? Wl2[n][k] : Wr2[n-128][k]   (layer-2, N-concat)
// Fragment: fi = ((k>>5)*16 + (n>>4))*64 + (n&15) + 16*((k&31)>>3), elem = k&7

__global__ __launch_bounds__(256) void setup_kernel(
    const float* __restrict__ x, _Float16* __restrict__ x16,
    const float* __restrict__ Wl1, const float* __restrict__ Wr1,
    const float* __restrict__ Wl2, const float* __restrict__ Wr2,
    _Float16* __restrict__ B1h, _Float16* __restrict__ B1l,
    _Float16* __restrict__ B2h, _Float16* __restrict__ B2l,
    int* __restrict__ counts) {
    int bid = blockIdx.x;
    int t = threadIdx.x;
    if (bid < ZERO_BLOCKS) {
        int i = bid * 256 + t;
        if (i < N_NODES) counts[i] = 0;
        return;
    }
    bid -= ZERO_BLOCKS;
    if (bid < 256) {
        int k = bid;   // 0..255
        int n = t;     // 0..255
        float v1 = (k < 128) ? Wl1[n * 128 + k] : Wr1[n * 128 + (k - 128)];
        float v2 = (n < 128) ? Wl2[n * 256 + k] : Wr2[(n - 128) * 256 + k];
        size_t fi = ((size_t)((k >> 5) * 16 + (n >> 4)) * 64 +
                     ((n & 15) + 16 * ((k & 31) >> 3))) * 8 + (k & 7);
        _Float16 h1 = (_Float16)v1;
        _Float16 h2 = (_Float16)v2;
        B1h[fi] = h1; B1l[fi] = (_Float16)(v1 - (float)h1);
        B2h[fi] = h2; B2l[fi] = (_Float16)(v2 - (float)h2);
        return;
    }
    bid -= 256;
    int i = bid * 256 + t;
    if (i < N_NODES * 32) {
        float4 v = reinterpret_cast<const float4*>(x)[i];
        half4 o = {(_Float16)v.x, (_Float16)v.y, (_Float16)v.z, (_Float16)v.w};
        reinterpret_cast<half4*>(x16)[i] = o;
    }
}

// ---------------- bucket-CSR build: one pass, uint16 slots ----------------
// XCD-partitioned (block i handles dst range (i&7)): counts/eidx lines are
// XCD-exclusive. uint16 slots halve the bucket array (4.8 MB total, 600 KB
// per-XCD slice) -> half the write-allocate fetches and dirty-line churn.

__global__ __launch_bounds__(256) void fill_kernel(const int* __restrict__ src,
                                                   const int* __restrict__ dst,
                                                   int* __restrict__ counts,
                                                   unsigned short* __restrict__ eidx, int E4) {
    int xcd = blockIdx.x & 7;
    int cb = blockIdx.x >> 3;
    int lo = xcd * NPR, hi = lo + NPR;
    int stride = (gridDim.x >> 3) * blockDim.x;  // in int4 units
    const iv4* src4 = reinterpret_cast<const iv4*>(src);
    const iv4* dst4 = reinterpret_cast<const iv4*>(dst);
    for (int q = cb * blockDim.x + threadIdx.x; q < E4; q += stride) {
        iv4 d4 = __builtin_nontemporal_load(&dst4[q]);
        iv4 s4 = __builtin_nontemporal_load(&src4[q]);
#pragma unroll
        for (int u = 0; u < 4; u++) {
            int d = d4[u];
            if (d >= lo && d < hi) {
                int pos = atomicAdd(&counts[d], 1);
                if (pos < CAP) eidx[d * CAP + pos] = (unsigned short)s4[u];
            }
        }
    }
}

// ---------------- mean-aggregation gather (one wave per dst node, fp16 rows) ----------------
// OMODE 0: write mean as fp16.  OMODE 1: add mean into fp32 out.

template <int OMODE>
__global__ __launch_bounds__(256) void gather_kernel(
    const unsigned short* __restrict__ eidx, const int* __restrict__ counts,
    const _Float16* __restrict__ xin, void* __restrict__ outp) {
    int wid = (blockIdx.x * 256 + threadIdx.x) >> 6;
    int lane = threadIdx.x & 63;
    if (wid >= N_NODES) return;
    int c = counts[wid];
    int end = c < CAP ? c : CAP;
    int base = wid * CAP;
    int half = lane >> 5;
    int c4 = lane & 31;
    float4 acc = {0, 0, 0, 0};
    int j = half;
    for (; j + 6 < end; j += 8) {
        int s0 = eidx[base + j],     s1 = eidx[base + j + 2];
        int s2 = eidx[base + j + 4], s3 = eidx[base + j + 6];
        half4 v0 = *reinterpret_cast<const half4*>(&xin[(size_t)s0 * 128 + c4 * 4]);
        half4 v1 = *reinterpret_cast<const half4*>(&xin[(size_t)s1 * 128 + c4 * 4]);
        half4 v2 = *reinterpret_cast<const half4*>(&xin[(size_t)s2 * 128 + c4 * 4]);
        half4 v3 = *reinterpret_cast<const half4*>(&xin[(size_t)s3 * 128 + c4 * 4]);
        acc.x += (float)v0.x + (float)v1.x + (float)v2.x + (float)v3.x;
        acc.y += (float)v0.y + (float)v1.y + (float)v2.y + (float)v3.y;
        acc.z += (float)v0.z + (float)v1.z + (float)v2.z + (float)v3.z;
        acc.w += (float)v0.w + (float)v1.w + (float)v2.w + (float)v3.w;
    }
    for (; j < end; j += 2) {
        int s0 = eidx[base + j];
        half4 v0 = *reinterpret_cast<const half4*>(&xin[(size_t)s0 * 128 + c4 * 4]);
        acc.x += (float)v0.x; acc.y += (float)v0.y; acc.z += (float)v0.z; acc.w += (float)v0.w;
    }
    acc.x += __shfl_xor(acc.x, 32);
    acc.y += __shfl_xor(acc.y, 32);
    acc.z += __shfl_xor(acc.z, 32);
    acc.w += __shfl_xor(acc.w, 32);
    if (half == 0) {
        float w = 1.0f / fmaxf((float)c, 1.0f);
        if (OMODE == 0) {
            half4 r = {(_Float16)(acc.x * w), (_Float16)(acc.y * w),
                       (_Float16)(acc.z * w), (_Float16)(acc.w * w)};
            *reinterpret_cast<half4*>(&((_Float16*)outp)[(size_t)wid * 128 + c4 * 4]) = r;
        } else {
            float* p = &((float*)outp)[(size_t)wid * 128 + c4 * 4];
            float4 old = *reinterpret_cast<float4*>(p);
            float4 r = {old.x + acc.x * w, old.y + acc.y * w,
                        old.z + acc.z * w, old.w + acc.w * w};
            *reinterpret_cast<float4*>(p) = r;
        }
    }
}

// ---------------- fp16 MFMA GEMM: full-K LDS panel, one barrier, merged N ----------------
// C[M, 256] = A[M, 256] @ B[256, 256] via A*Bh + A*Bl (A exact fp16, fp32 accum).
// MODE 0: A = [A0=agg16 | A1=x16] (K-concat); relu(C + b1) -> O0 = h16 (fp16 [M,256])
// MODE 1: A = A0 = h16; C[:,0:128] -> O0 = z16 (fp16); C[:,128:256]+b2 -> O1 = out (fp32)
// Block: 128 rows x all 256 cols, 512 threads = 8 waves (2 wm x 4 wn);
// per-wave 64x64 out = 4x4 frags of 16x16x32. A panel (128x256 fp16 = 64 KB) staged once.
template <int MODE>
__global__ __launch_bounds__(512, 4) void mfma_gemm_kernel(
    const _Float16* __restrict__ A0, const _Float16* __restrict__ A1,
    const _Float16* __restrict__ Bh, const _Float16* __restrict__ Bl,
    const float* __restrict__ bias, void* __restrict__ O0v, float* __restrict__ O1) {
    __shared__ _Float16 lA[8][8][64][8];  // [kt][m_blk][lane][elem] = 64 KB
    const int tid = threadIdx.x;
    const int lane = tid & 63;
    const int w = tid >> 6;
    const int wm = w >> 2, wn = w & 3;
    const int m0 = blockIdx.x * 128;
    const int nb0 = wn * 4;

    f32x4 acc[4][4];
#pragma unroll
    for (int i = 0; i < 4; i++)
#pragma unroll
        for (int j = 0; j < 4; j++) acc[i][j] = f32x4{0.f, 0.f, 0.f, 0.f};

    // Stage the full 128x256 A panel in fragment order. Thread -> row ms, chunks c0+4i.
    const int ms = tid >> 2;   // 0..127
    const int c0 = tid & 3;    // 16B chunk phase
    {
        int node = m0 + ms;
#pragma unroll
        for (int i = 0; i < 8; i++) {
            int c = c0 + 4 * i;  // 0..31: 16B chunk along K
            const _Float16* Asrc;
            int koff;
            if (MODE == 0) {
                Asrc = (c < 16) ? A0 : A1;
                koff = (c & 15) * 8;
            } else {
                Asrc = A0;
                koff = c * 8;
            }
            half8 v = {0, 0, 0, 0, 0, 0, 0, 0};
            if (node < N_NODES)
                v = *reinterpret_cast<const half8*>(
                    &Asrc[(size_t)node * (MODE == 0 ? 128 : 256) + koff]);
            *reinterpret_cast<half8*>(&lA[c >> 2][ms >> 4][(ms & 15) + 16 * (c & 3)][0]) = v;
        }
    }
    __syncthreads();  // the only barrier

    for (int kt = 0; kt < 8; kt++) {
        half8 ah[4];
#pragma unroll
        for (int mb = 0; mb < 4; mb++)
            ah[mb] = *reinterpret_cast<const half8*>(&lA[kt][wm * 4 + mb][lane][0]);
#pragma unroll
        for (int nb = 0; nb < 4; nb++) {
            size_t fi = ((size_t)(kt * 16 + nb0 + nb) * 64 + lane) * 8;
            half8 vh = *reinterpret_cast<const half8*>(&Bh[fi]);
            half8 vl = *reinterpret_cast<const half8*>(&Bl[fi]);
            __builtin_amdgcn_s_setprio(1);
#pragma unroll
            for (int mb = 0; mb < 4; mb++) {
                acc[mb][nb] = __builtin_amdgcn_mfma_f32_16x16x32_f16(ah[mb], vh, acc[mb][nb], 0, 0, 0);
                acc[mb][nb] = __builtin_amdgcn_mfma_f32_16x16x32_f16(ah[mb], vl, acc[mb][nb], 0, 0, 0);
            }
            __builtin_amdgcn_s_setprio(0);
        }
    }

    // epilogue: C/D layout col = lane&15, row = (lane>>4)*4 + reg
#pragma unroll
    for (int mb = 0; mb < 4; mb++) {
        int rbase = m0 + wm * 64 + mb * 16 + ((lane >> 4) << 2);
#pragma unroll
        for (int nb = 0; nb < 4; nb++) {
            int col = wn * 64 + nb * 16 + (lane & 15);   // 0..255
#pragma unroll
            for (int r = 0; r < 4; r++) {
                int row = rbase + r;
                if (row >= N_NODES) continue;
                float vv = acc[mb][nb][r];
                if (MODE == 0) {
                    ((_Float16*)O0v)[(size_t)row * 256 + col] =
                        (_Float16)fmaxf(vv + bias[col], 0.0f);
                } else {
                    if (col < 128)
                        ((_Float16*)O0v)[(size_t)row * 128 + col] = (_Float16)vv;
                    else
                        O1[(size_t)row * 128 + (col - 128)] = vv + bias[col - 128];
                }
            }
        }
    }
}

extern "C" void kernel_launch(void* const* d_in, const int* in_sizes, int n_in,
                              void* d_out, int out_size, void* d_ws, size_t ws_size,
                              hipStream_t stream) {
    const float* x   = (const float*)d_in[0];
    const int*   ei  = (const int*)d_in[1];
    const float* Wl1 = (const float*)d_in[2];
    const float* Wr1 = (const float*)d_in[3];
    const float* b1  = (const float*)d_in[4];
    const float* Wl2 = (const float*)d_in[5];
    const float* Wr2 = (const float*)d_in[6];
    const float* b2  = (const float*)d_in[7];
    float* out = (float*)d_out;

    const int* srcp = ei;            // edge_index[0]
    const int* dstp = ei + N_EDGES;  // edge_index[1]

    // Workspace layout
    int*            counts = (int*)d_ws;                         // N
    unsigned short* eidx   = (unsigned short*)(counts + N_NODES); // N*CAP uint16
    _Float16*       B1h    = (_Float16*)(eidx + N_NODES * CAP);  // 65536 halfs each
    _Float16*       B1l    = B1h + 65536;
    _Float16*       B2h    = B1l + 65536;
    _Float16*       B2l    = B2h + 65536;
    _Float16*       agg16  = B2l + 65536;                        // N*128 (reused as z16)
    _Float16*       x16    = agg16 + (size_t)N_NODES * 128;      // N*128
    _Float16*       h16    = x16 + (size_t)N_NODES * 128;        // N*256
    _Float16*       z16    = agg16;                              // alias: agg dead after gemm1

    setup_kernel<<<ZERO_BLOCKS + 256 + CVT_BLOCKS, 256, 0, stream>>>(
        x, x16, Wl1, Wr1, Wl2, Wr2, B1h, B1l, B2h, B2l, counts);
    fill_kernel<<<8 * CB, 256, 0, stream>>>(srcp, dstp, counts, eidx, N_EDGES / 4);

    int ggrid = (N_NODES + 127) / 128;  // 391

    // Layer 1: agg16 = mean-aggr(x16); h16 = relu([agg16|x16]@B1 + b1)
    gather_kernel<0><<<(N_NODES * 64 + 255) / 256, 256, 0, stream>>>(
        eidx, counts, x16, (void*)agg16);
    mfma_gemm_kernel<0><<<ggrid, 512, 0, stream>>>(agg16, x16, B1h, B1l, b1, (void*)h16, nullptr);

    // Layer 2: [z16|pre_out] = h16@B2 (+b2 on out half); out += mean-aggr(z16)
    mfma_gemm_kernel<1><<<ggrid, 512, 0, stream>>>(h16, nullptr, B2h, B2l, b2, (void*)z16, out);
    gather_kernel<1><<<(N_NODES * 64 + 255) / 256, 256, 0, stream>>>(
        eidx, counts, z16, (void*)out);
}